// Round 7
// baseline (187.405 us; speedup 1.0000x reference)
//
#include <hip/hip_runtime.h>
#include <hip/hip_bf16.h>

#define NH 12
#define HD 64
#define SEQ 2048
#define DM 768

typedef __attribute__((ext_vector_type(8))) short bf16x8;
typedef __attribute__((ext_vector_type(4))) short bf16x4;
typedef __attribute__((ext_vector_type(4))) float f32x4;

static __device__ __forceinline__ unsigned short f2bf(float f) {
  unsigned int u = __float_as_uint(f);
  u += 0x7fff + ((u >> 16) & 1);   // round-to-nearest-even
  return (unsigned short)(u >> 16);
}

static __device__ __forceinline__ unsigned cvt_pk_bf16(float lo, float hi) {
  unsigned r;
  asm("v_cvt_pk_bf16_f32 %0, %1, %2" : "=v"(r) : "v"(lo), "v"(hi));
  return r;
}

static __device__ __forceinline__ void gload_lds16(const void* g, void* l) {
  __builtin_amdgcn_global_load_lds(
      (const __attribute__((address_space(1))) void*)g,
      (__attribute__((address_space(3))) void*)l, 16, 0, 0);
}

static __device__ __forceinline__ bf16x8 cat4(bf16x4 a, bf16x4 b) {
  bf16x8 r;
  r[0] = a[0]; r[1] = a[1]; r[2] = a[2]; r[3] = a[3];
  r[4] = b[0]; r[5] = b[1]; r[6] = b[2]; r[7] = b[3];
  return r;
}

// q-store scale: sqrt(log2(e))/8 — folds the 1/64 attention scale and the
// base-2 exp conversion into q at the QKV store.
#define QSCALE 0.15014030f

// ---------------------------------------------------------------------------
// Kernel 0: f32 -> bf16 bulk convert (vector x8), grid-stride.
// ---------------------------------------------------------------------------
__global__ __launch_bounds__(256) void cvt_kernel(
    const float* __restrict__ src, unsigned short* __restrict__ dst, int n8) {
  int i = blockIdx.x * 256 + threadIdx.x;
  const int stride = gridDim.x * 256;
  for (; i < n8; i += stride) {
    const float4 a = reinterpret_cast<const float4*>(src)[i * 2];
    const float4 b = reinterpret_cast<const float4*>(src)[i * 2 + 1];
    ushort4 lo = make_ushort4(f2bf(a.x), f2bf(a.y), f2bf(a.z), f2bf(a.w));
    ushort4 hi = make_ushort4(f2bf(b.x), f2bf(b.y), f2bf(b.z), f2bf(b.w));
    reinterpret_cast<ushort4*>(dst)[i * 2] = lo;
    reinterpret_cast<ushort4*>(dst)[i * 2 + 1] = hi;
  }
}

// ---------------------------------------------------------------------------
// Kernel 1: qkv = xb @ wb^T + b (bf16 in). 128x128 tile, BK=32, dbuf LDS via
// global_load_lds (slot-swizzled source + read; 1 syncthreads per K-step).
// q stored (B,H,S,HD) bf16 pre-scaled by QSCALE; v stored (B,H,HD,S) bf16.
// ---------------------------------------------------------------------------
__global__ __launch_bounds__(256) void qkv_kernel(
    const unsigned short* __restrict__ xb, const unsigned short* __restrict__ wb,
    const float* __restrict__ bias,
    unsigned short* __restrict__ qb, unsigned short* __restrict__ vtb) {
  __shared__ alignas(16) char As[2][8192];   // [128 rows][64B], slot-swizzled
  __shared__ alignas(16) char Bs[2][8192];
  const int tid = threadIdx.x;
  const int lane = tid & 63, wid = tid >> 6;
  const int wr = wid >> 1, wc = wid & 1;
  const int g = lane >> 4, c = lane & 15;
  const int m0 = blockIdx.x * 128, n0 = blockIdx.y * 128;
  const char* Ab = (const char*)xb;
  const char* Bb = (const char*)wb;

  // staging: physical o -> row r=o>>6; source slot = ((o>>4)&3) ^ ((r>>1)&3)
  const int o0 = tid * 16, o1 = tid * 16 + 4096;
  const int r0 = o0 >> 6, r1 = o1 >> 6;
  const int sw0 = (o0 & 63) ^ (((r0 >> 1) & 3) << 4);
  const int sw1 = (o1 & 63) ^ (((r1 >> 1) & 3) << 4);

  auto stage = [&](int kt, int buf) {
    const int k0b = kt * 64;
    gload_lds16(Ab + (size_t)(m0 + r0) * 1536 + k0b + sw0, &As[buf][o0]);
    gload_lds16(Bb + (size_t)(n0 + r0) * 1536 + k0b + sw0, &Bs[buf][o0]);
    gload_lds16(Ab + (size_t)(m0 + r1) * 1536 + k0b + sw1, &As[buf][o1]);
    gload_lds16(Bb + (size_t)(n0 + r1) * 1536 + k0b + sw1, &Bs[buf][o1]);
  };

  f32x4 acc[4][4] = {};
  stage(0, 0);

  for (int kt = 0; kt < 24; ++kt) {
    __syncthreads();                       // drains vmcnt: stage(kt) landed
    if (kt < 23) stage(kt + 1, (kt + 1) & 1);
    const char* Ap = As[kt & 1];
    const char* Bp = Bs[kt & 1];
    bf16x8 a_f[4], b_f[4];
#pragma unroll
    for (int i = 0; i < 4; ++i) {
      const int ra = wr * 64 + i * 16 + c;
      const int rb = wc * 64 + i * 16 + c;
      a_f[i] = *reinterpret_cast<const bf16x8*>(Ap + ra * 64 + ((g ^ ((ra >> 1) & 3)) << 4));
      b_f[i] = *reinterpret_cast<const bf16x8*>(Bp + rb * 64 + ((g ^ ((rb >> 1) & 3)) << 4));
    }
#pragma unroll
    for (int ai = 0; ai < 4; ++ai)
#pragma unroll
      for (int ni = 0; ni < 4; ++ni)
        acc[ai][ni] = __builtin_amdgcn_mfma_f32_16x16x32_bf16(a_f[ai], b_f[ni], acc[ai][ni], 0, 0, 0);
  }

#pragma unroll
  for (int ni = 0; ni < 4; ++ni) {
    const int n = n0 + wc * 64 + ni * 16 + c;
    const float bn = bias[n];
    if (n < DM) {  // q path: (B,H,S,HD), pre-scaled
      const int h = n >> 6, d = n & 63;
#pragma unroll
      for (int ai = 0; ai < 4; ++ai)
#pragma unroll
        for (int r = 0; r < 4; ++r) {
          const int m = m0 + wr * 64 + ai * 16 + g * 4 + r;
          const int bb = m >> 11, s = m & 2047;
          qb[(((size_t)(bb * NH + h)) * SEQ + s) * HD + d] = f2bf((acc[ai][ni][r] + bn) * QSCALE);
        }
    } else {  // v path: transposed (B,H,HD,S)
      const int nn = n - DM;
      const int h = nn >> 6, d = nn & 63;
#pragma unroll
      for (int ai = 0; ai < 4; ++ai) {
        const int m_base = m0 + wr * 64 + ai * 16 + g * 4;
        const int bb = m_base >> 11, s0 = m_base & 2047;
        ushort4 pk = make_ushort4(f2bf(acc[ai][ni][0] + bn), f2bf(acc[ai][ni][1] + bn),
                                  f2bf(acc[ai][ni][2] + bn), f2bf(acc[ai][ni][3] + bn));
        *reinterpret_cast<ushort4*>(
            &vtb[((size_t)(bb * NH + h) * HD + d) * SEQ + s0]) = pk;
      }
    }
  }
}

// ---------------------------------------------------------------------------
// Kernel 2: flash attention, Q == K (pre-scaled), fixed-max base-2 softmax.
// XCD-affinity 1D grid: all 32 q-blocks of a bh map to one XCD (L2-local K/V).
// Wave-private k-split (16 rows/wave), NO barriers in main loop. K staged via
// global_load_lds into 4 rotating wave-private strips (counted vmcnt, never
// drained); V read direct global->reg, pair-deep. PV pair-merged into K=32.
// ---------------------------------------------------------------------------
__global__ __launch_bounds__(256) void attn_kernel(
    const unsigned short* __restrict__ qb, const unsigned short* __restrict__ vtb,
    unsigned short* __restrict__ ao) {
  __shared__ alignas(16) char pool[32768];   // 4 K-bufs x (4 waves x 2KB); epi reuses
  __shared__ alignas(16) float lsum[4][64];

  const int tid = threadIdx.x;
  const int lane = tid & 63, wid = tid >> 6;
  const int g = lane >> 4, c = lane & 15;

  // XCD-grouped decode: wg = xcd + 8*(qblk + 32*bh_local), bh = xcd*6+bh_local
  const int wg = blockIdx.x;
  const int xcd = wg & 7;
  const int idx = wg >> 3;                 // 0..191
  const int bh = xcd * 6 + (idx >> 5);
  const int qs0 = (idx & 31) * 64;
  const size_t base = (size_t)bh * SEQ * HD;

  // Q B-frags: lane (c,g) holds Q[qs0+jq*16+c][ks*32+g*8..+7]
  bf16x8 qf[4][2];
#pragma unroll
  for (int jq = 0; jq < 4; ++jq) {
    const unsigned short* qrow = &qb[base + (size_t)(qs0 + jq * 16 + c) * HD + g * 8];
    qf[jq][0] = *reinterpret_cast<const bf16x8*>(qrow);
    qf[jq][1] = *reinterpret_cast<const bf16x8*>(qrow + 32);
  }

  // K staging (wave-private 2KB strip = wave's 16 k-rows, XOR-swizzled)
  const char* kSrc = (const char*)qb + base * 2 + (size_t)wid * 2048;
  const int ko0 = lane * 16, ko1 = lane * 16 + 1024;
  const int ks0s = ko0 ^ (((ko0 >> 7) & 7) << 4);
  const int ks1s = ko1 ^ (((ko1 >> 7) & 7) << 4);
  auto stageK = [&](int t, int buf) {
    char* strip = pool + buf * 8192 + wid * 2048;
    gload_lds16(kSrc + (size_t)t * 8192 + ks0s, strip + ko0);
    gload_lds16(kSrc + (size_t)t * 8192 + ks1s, strip + ko1);
  };
  const int kx0 = c * 128 + ((g * 16) ^ ((c & 7) << 4));
  const int kx1 = c * 128 + ((64 + g * 16) ^ ((c & 7) << 4));
  auto loadK = [&](int buf, bf16x8* kf) {
    const char* strip = pool + buf * 8192 + wid * 2048;
    kf[0] = *reinterpret_cast<const bf16x8*>(strip + kx0);
    kf[1] = *reinterpret_cast<const bf16x8*>(strip + kx1);
  };

  // V direct-load bases: vf[dn] = V^T[d=dn*16+c][k = t*64 + wid*16 + 4g..+3]
  const char* vp0 = (const char*)vtb + ((size_t)(bh * HD) * SEQ) * 2 + wid * 32 + g * 8;

  float l_p[4] = {};
  f32x4 o_acc[4][4] = {};  // [dn][jq]: O[d=dn*16+4g+r][q=jq*16+c] (partial k)

  auto qk = [&](const bf16x8* kf, f32x4* s) {
    __builtin_amdgcn_s_setprio(1);
#pragma unroll
    for (int jq = 0; jq < 4; ++jq)
      s[jq] = __builtin_amdgcn_mfma_f32_16x16x32_bf16(kf[0], qf[jq][0], s[jq], 0, 0, 0);
#pragma unroll
    for (int jq = 0; jq < 4; ++jq)
      s[jq] = __builtin_amdgcn_mfma_f32_16x16x32_bf16(kf[1], qf[jq][1], s[jq], 0, 0, 0);
    __builtin_amdgcn_s_setprio(0);
  };
  auto expcvt = [&](const f32x4* s, bf16x4* pb) {
#pragma unroll
    for (int jq = 0; jq < 4; ++jq) {
      float p0 = __builtin_amdgcn_exp2f(s[jq][0]);
      float p1 = __builtin_amdgcn_exp2f(s[jq][1]);
      float p2 = __builtin_amdgcn_exp2f(s[jq][2]);
      float p3 = __builtin_amdgcn_exp2f(s[jq][3]);
      l_p[jq] += (p0 + p1) + (p2 + p3);
      uint2 wv = make_uint2(cvt_pk_bf16(p0, p1), cvt_pk_bf16(p2, p3));
      pb[jq] = *reinterpret_cast<bf16x4*>(&wv);
    }
  };

  stageK(0, 0);
  stageK(1, 1);

  for (int t = 0; t < 32; t += 2) {
    // WAR: strips (t+2)&3,(t+3)&3 hold tiles t-2,t-1 whose ds_reads are retired
    asm volatile("s_waitcnt lgkmcnt(0)" ::: "memory");
    __builtin_amdgcn_sched_barrier(0);

    // V loads for the pair (used at PV, ~full pair of latency cover)
    bf16x4 vfA[4], vfB[4];
#pragma unroll
    for (int dn = 0; dn < 4; ++dn)
      vfA[dn] = *reinterpret_cast<const bf16x4*>(vp0 + (size_t)(dn * 16 + c) * (SEQ * 2) + (size_t)t * 128);
#pragma unroll
    for (int dn = 0; dn < 4; ++dn)
      vfB[dn] = *reinterpret_cast<const bf16x4*>(vp0 + (size_t)(dn * 16 + c) * (SEQ * 2) + (size_t)(t + 1) * 128);
    __builtin_amdgcn_sched_barrier(0);

    stageK(t + 2, (t + 2) & 3);   // t+2/t+3 may exceed 31: benign garbage prefetch
    stageK(t + 3, (t + 3) & 3);
    __builtin_amdgcn_sched_barrier(0);

    // newest-14 = [V pair(8), K(t+2),K(t+3)(4), K(t+1)(2)] -> K(t) landed
    asm volatile("s_waitcnt vmcnt(14)" ::: "memory");
    __builtin_amdgcn_sched_barrier(0);
    bf16x8 kf0[2];
    loadK(t & 3, kf0);
    f32x4 sa0[4] = {};
    qk(kf0, sa0);
    bf16x4 pb0[4];
    expcvt(sa0, pb0);

    // newest-12 = [V pair(8), K(t+2),K(t+3)(4)] -> K(t+1) landed
    asm volatile("s_waitcnt vmcnt(12)" ::: "memory");
    __builtin_amdgcn_sched_barrier(0);
    bf16x8 kf1[2];
    loadK((t + 1) & 3, kf1);
    f32x4 sa1[4] = {};
    qk(kf1, sa1);
    bf16x4 pb1[4];
    expcvt(sa1, pb1);

    // newest-4 = [K(t+2),K(t+3)] -> V pair landed
    asm volatile("s_waitcnt vmcnt(4)" ::: "memory");
    __builtin_amdgcn_sched_barrier(0);

    // PV pair: K=32, slots [tile t k(4g..4g+3) | tile t+1 k(4g..4g+3)]
    bf16x8 pvv[4];
#pragma unroll
    for (int jq = 0; jq < 4; ++jq) pvv[jq] = cat4(pb0[jq], pb1[jq]);
    __builtin_amdgcn_s_setprio(1);
#pragma unroll
    for (int dn = 0; dn < 4; ++dn) {
      const bf16x8 av = cat4(vfA[dn], vfB[dn]);
#pragma unroll
      for (int jq = 0; jq < 4; ++jq)
        o_acc[dn][jq] = __builtin_amdgcn_mfma_f32_16x16x32_bf16(av, pvv[jq], o_acc[dn][jq], 0, 0, 0);
    }
    __builtin_amdgcn_s_setprio(0);
  }

  // ---- epilogue: l reduce; cross-wave O reduction via single sA buffer ----
#pragma unroll
  for (int jq = 0; jq < 4; ++jq) {
    float v = l_p[jq];
    v += __shfl_xor(v, 16);
    v += __shfl_xor(v, 32);
    if (g == 0) lsum[wid][jq * 16 + c] = v;
  }
  __syncthreads();  // drains garbage K stages + lsum writes; pool reusable

  float* sA = (float*)pool;  // [64][68] f32 = 17408 B
  auto writeO = [&]() {
#pragma unroll
    for (int dn = 0; dn < 4; ++dn)
#pragma unroll
      for (int jq = 0; jq < 4; ++jq)
        *reinterpret_cast<f32x4*>(&sA[(jq * 16 + c) * 68 + dn * 16 + 4 * g]) = o_acc[dn][jq];
  };
  auto addO = [&]() {
#pragma unroll
    for (int dn = 0; dn < 4; ++dn)
#pragma unroll
      for (int jq = 0; jq < 4; ++jq)
        o_acc[dn][jq] += *reinterpret_cast<const f32x4*>(&sA[(jq * 16 + c) * 68 + dn * 16 + 4 * g]);
  };

#pragma unroll
  for (int w = 1; w < 4; ++w) {
    if (wid == w) writeO();
    __syncthreads();
    if (wid == 0) addO();
    __syncthreads();
  }
  if (wid == 0) {
    const int b = bh / NH, h = bh % NH;
    float linv[4];
#pragma unroll
    for (int jq = 0; jq < 4; ++jq) {
      const int q = jq * 16 + c;
      const float l = (lsum[0][q] + lsum[1][q]) + (lsum[2][q] + lsum[3][q]);
      linv[jq] = __builtin_amdgcn_rcpf(l);
    }
#pragma unroll
    for (int dn = 0; dn < 4; ++dn)
#pragma unroll
      for (int jq = 0; jq < 4; ++jq) {
        uint2 wv = make_uint2(
            cvt_pk_bf16(o_acc[dn][jq][0] * linv[jq], o_acc[dn][jq][1] * linv[jq]),
            cvt_pk_bf16(o_acc[dn][jq][2] * linv[jq], o_acc[dn][jq][3] * linv[jq]));
        *reinterpret_cast<uint2*>(
            &ao[((size_t)b * SEQ + qs0 + jq * 16 + c) * DM + h * HD + dn * 16 + 4 * g]) = wv;
      }
  }
}

// ---------------------------------------------------------------------------
// Kernel 3: out = ao @ pwb^T + proj_b (bf16 in, f32 out). Same staging as qkv.
// ---------------------------------------------------------------------------
__global__ __launch_bounds__(256) void proj_kernel(
    const unsigned short* __restrict__ ao, const unsigned short* __restrict__ pwb,
    const float* __restrict__ bias, float* __restrict__ out) {
  __shared__ alignas(16) char As[2][8192];
  __shared__ alignas(16) char Bs[2][8192];
  const int tid = threadIdx.x;
  const int lane = tid & 63, wid = tid >> 6;
  const int wr = wid >> 1, wc = wid & 1;
  const int g = lane >> 4, c = lane & 15;
  const int m0 = blockIdx.x * 128, n0 = blockIdx.y * 128;
  const char* Ab = (const char*)ao;
  const char* Bb = (const char*)pwb;

  const int o0 = tid * 16, o1 = tid * 16 + 4096;
  const int r0 = o0 >> 6, r1 = o1 >> 6;
  const int sw0 = (o0 & 63) ^ (((r0 >> 1) & 3) << 4);
  const int sw1 = (o1 & 63) ^ (((r1 >> 1) & 3) << 4);

  auto stage = [&](int kt, int buf) {
    const int k0b = kt * 64;
    gload_lds16(Ab + (size_t)(m0 + r0) * 1536 + k0b + sw0, &As[buf][o0]);
    gload_lds16(Bb + (size_t)(n0 + r0) * 1536 + k0b + sw0, &Bs[buf][o0]);
    gload_lds16(Ab + (size_t)(m0 + r1) * 1536 + k0b + sw1, &As[buf][o1]);
    gload_lds16(Bb + (size_t)(n0 + r1) * 1536 + k0b + sw1, &Bs[buf][o1]);
  };

  f32x4 acc[4][4] = {};
  stage(0, 0);

  for (int kt = 0; kt < 24; ++kt) {
    __syncthreads();
    if (kt < 23) stage(kt + 1, (kt + 1) & 1);
    const char* Ap = As[kt & 1];
    const char* Bp = Bs[kt & 1];
    bf16x8 a_f[4], b_f[4];
#pragma unroll
    for (int i = 0; i < 4; ++i) {
      const int ra = wr * 64 + i * 16 + c;
      const int rb = wc * 64 + i * 16 + c;
      a_f[i] = *reinterpret_cast<const bf16x8*>(Ap + ra * 64 + ((g ^ ((ra >> 1) & 3)) << 4));
      b_f[i] = *reinterpret_cast<const bf16x8*>(Bp + rb * 64 + ((g ^ ((rb >> 1) & 3)) << 4));
    }
#pragma unroll
    for (int ai = 0; ai < 4; ++ai)
#pragma unroll
      for (int ni = 0; ni < 4; ++ni)
        acc[ai][ni] = __builtin_amdgcn_mfma_f32_16x16x32_bf16(a_f[ai], b_f[ni], acc[ai][ni], 0, 0, 0);
  }

#pragma unroll
  for (int ni = 0; ni < 4; ++ni) {
    const int n = n0 + wc * 64 + ni * 16 + c;
    const float bn = bias[n];
#pragma unroll
    for (int ai = 0; ai < 4; ++ai)
#pragma unroll
      for (int r = 0; r < 4; ++r) {
        const int m = m0 + wr * 64 + ai * 16 + g * 4 + r;
        out[(size_t)m * DM + n] = acc[ai][ni][r] + bn;
      }
  }
}

extern "C" void kernel_launch(void* const* d_in, const int* in_sizes, int n_in,
                              void* d_out, int out_size, void* d_ws, size_t ws_size,
                              hipStream_t stream) {
  const float* x = (const float*)d_in[0];
  const float* qkv_w = (const float*)d_in[1];
  const float* qkv_b = (const float*)d_in[2];
  const float* proj_w = (const float*)d_in[3];
  const float* proj_b = (const float*)d_in[4];
  float* out = (float*)d_out;

  const size_t elems = (size_t)4 * NH * SEQ * HD;  // 6291456 = B*S*DM
  unsigned short* qbuf = (unsigned short*)d_ws;
  unsigned short* vtbuf = qbuf + elems;
  unsigned short* xbf = vtbuf + elems;       // aliases aobuf (disjoint lifetimes)
  unsigned short* aobuf = xbf;
  unsigned short* wqkvbf = xbf + elems;      // 1179648
  unsigned short* wprojbf = wqkvbf + (size_t)2 * DM * DM;  // 589824

  cvt_kernel<<<dim3(1024), 256, 0, stream>>>(x, xbf, (int)(elems / 8));
  cvt_kernel<<<dim3(576), 256, 0, stream>>>(qkv_w, wqkvbf, 2 * DM * DM / 8);
  cvt_kernel<<<dim3(288), 256, 0, stream>>>(proj_w, wprojbf, DM * DM / 8);

  qkv_kernel<<<dim3(64, 12), 256, 0, stream>>>(xbf, wqkvbf, qkv_b, qbuf, vtbuf);
  attn_kernel<<<dim3(1536), 256, 0, stream>>>(qbuf, vtbuf, aobuf);
  proj_kernel<<<dim3(64, 6), 256, 0, stream>>>(aobuf, wprojbf, proj_b, out);
}

// Round 8
// 165.042 us; speedup vs baseline: 1.1355x; 1.1355x over previous
//
#include <hip/hip_runtime.h>
#include <hip/hip_bf16.h>

#define NH 12
#define HD 64
#define SEQ 2048
#define DM 768

typedef __attribute__((ext_vector_type(8))) short bf16x8;
typedef __attribute__((ext_vector_type(4))) short bf16x4;
typedef __attribute__((ext_vector_type(4))) float f32x4;

static __device__ __forceinline__ unsigned short f2bf(float f) {
  unsigned int u = __float_as_uint(f);
  u += 0x7fff + ((u >> 16) & 1);   // round-to-nearest-even
  return (unsigned short)(u >> 16);
}

static __device__ __forceinline__ unsigned cvt_pk_bf16(float lo, float hi) {
  unsigned r;
  asm("v_cvt_pk_bf16_f32 %0, %1, %2" : "=v"(r) : "v"(lo), "v"(hi));
  return r;
}

static __device__ __forceinline__ void gload_lds16(const void* g, void* l) {
  __builtin_amdgcn_global_load_lds(
      (const __attribute__((address_space(1))) void*)g,
      (__attribute__((address_space(3))) void*)l, 16, 0, 0);
}

static __device__ __forceinline__ bf16x8 cat4(bf16x4 a, bf16x4 b) {
  bf16x8 r;
  r[0] = a[0]; r[1] = a[1]; r[2] = a[2]; r[3] = a[3];
  r[4] = b[0]; r[5] = b[1]; r[6] = b[2]; r[7] = b[3];
  return r;
}

// q-store scale: sqrt(log2(e))/8 — folds the 1/64 attention scale and the
// base-2 exp conversion into q at the QKV store.
#define QSCALE 0.15014030f

// ---------------------------------------------------------------------------
// Kernel 0: f32 -> bf16 bulk convert (vector x8), grid-stride.
// ---------------------------------------------------------------------------
__global__ __launch_bounds__(256) void cvt_kernel(
    const float* __restrict__ src, unsigned short* __restrict__ dst, int n8) {
  int i = blockIdx.x * 256 + threadIdx.x;
  const int stride = gridDim.x * 256;
  for (; i < n8; i += stride) {
    const float4 a = reinterpret_cast<const float4*>(src)[i * 2];
    const float4 b = reinterpret_cast<const float4*>(src)[i * 2 + 1];
    ushort4 lo = make_ushort4(f2bf(a.x), f2bf(a.y), f2bf(a.z), f2bf(a.w));
    ushort4 hi = make_ushort4(f2bf(b.x), f2bf(b.y), f2bf(b.z), f2bf(b.w));
    reinterpret_cast<ushort4*>(dst)[i * 2] = lo;
    reinterpret_cast<ushort4*>(dst)[i * 2 + 1] = hi;
  }
}

// ---------------------------------------------------------------------------
// Kernel 1: qkv = xb @ wb^T + b (bf16 in). 128x128 tile, BK=32, dbuf LDS via
// global_load_lds (slot-swizzled source + read; 1 syncthreads per K-step).
// q stored (B,H,S,HD) bf16 pre-scaled by QSCALE; v stored (B,H,HD,S) bf16.
// ---------------------------------------------------------------------------
__global__ __launch_bounds__(256) void qkv_kernel(
    const unsigned short* __restrict__ xb, const unsigned short* __restrict__ wb,
    const float* __restrict__ bias,
    unsigned short* __restrict__ qb, unsigned short* __restrict__ vtb) {
  __shared__ alignas(16) char As[2][8192];   // [128 rows][64B], slot-swizzled
  __shared__ alignas(16) char Bs[2][8192];
  const int tid = threadIdx.x;
  const int lane = tid & 63, wid = tid >> 6;
  const int wr = wid >> 1, wc = wid & 1;
  const int g = lane >> 4, c = lane & 15;
  const int m0 = blockIdx.x * 128, n0 = blockIdx.y * 128;
  const char* Ab = (const char*)xb;
  const char* Bb = (const char*)wb;

  // staging: physical o -> row r=o>>6; source slot = ((o>>4)&3) ^ ((r>>1)&3)
  const int o0 = tid * 16, o1 = tid * 16 + 4096;
  const int r0 = o0 >> 6, r1 = o1 >> 6;
  const int sw0 = (o0 & 63) ^ (((r0 >> 1) & 3) << 4);
  const int sw1 = (o1 & 63) ^ (((r1 >> 1) & 3) << 4);

  auto stage = [&](int kt, int buf) {
    const int k0b = kt * 64;
    gload_lds16(Ab + (size_t)(m0 + r0) * 1536 + k0b + sw0, &As[buf][o0]);
    gload_lds16(Bb + (size_t)(n0 + r0) * 1536 + k0b + sw0, &Bs[buf][o0]);
    gload_lds16(Ab + (size_t)(m0 + r1) * 1536 + k0b + sw1, &As[buf][o1]);
    gload_lds16(Bb + (size_t)(n0 + r1) * 1536 + k0b + sw1, &Bs[buf][o1]);
  };

  f32x4 acc[4][4] = {};
  stage(0, 0);

  for (int kt = 0; kt < 24; ++kt) {
    __syncthreads();                       // drains vmcnt: stage(kt) landed
    if (kt < 23) stage(kt + 1, (kt + 1) & 1);
    const char* Ap = As[kt & 1];
    const char* Bp = Bs[kt & 1];
    bf16x8 a_f[4], b_f[4];
#pragma unroll
    for (int i = 0; i < 4; ++i) {
      const int ra = wr * 64 + i * 16 + c;
      const int rb = wc * 64 + i * 16 + c;
      a_f[i] = *reinterpret_cast<const bf16x8*>(Ap + ra * 64 + ((g ^ ((ra >> 1) & 3)) << 4));
      b_f[i] = *reinterpret_cast<const bf16x8*>(Bp + rb * 64 + ((g ^ ((rb >> 1) & 3)) << 4));
    }
#pragma unroll
    for (int ai = 0; ai < 4; ++ai)
#pragma unroll
      for (int ni = 0; ni < 4; ++ni)
        acc[ai][ni] = __builtin_amdgcn_mfma_f32_16x16x32_bf16(a_f[ai], b_f[ni], acc[ai][ni], 0, 0, 0);
  }

#pragma unroll
  for (int ni = 0; ni < 4; ++ni) {
    const int n = n0 + wc * 64 + ni * 16 + c;
    const float bn = bias[n];
    if (n < DM) {  // q path: (B,H,S,HD), pre-scaled
      const int h = n >> 6, d = n & 63;
#pragma unroll
      for (int ai = 0; ai < 4; ++ai)
#pragma unroll
        for (int r = 0; r < 4; ++r) {
          const int m = m0 + wr * 64 + ai * 16 + g * 4 + r;
          const int bb = m >> 11, s = m & 2047;
          qb[(((size_t)(bb * NH + h)) * SEQ + s) * HD + d] = f2bf((acc[ai][ni][r] + bn) * QSCALE);
        }
    } else {  // v path: transposed (B,H,HD,S)
      const int nn = n - DM;
      const int h = nn >> 6, d = nn & 63;
#pragma unroll
      for (int ai = 0; ai < 4; ++ai) {
        const int m_base = m0 + wr * 64 + ai * 16 + g * 4;
        const int bb = m_base >> 11, s0 = m_base & 2047;
        ushort4 pk = make_ushort4(f2bf(acc[ai][ni][0] + bn), f2bf(acc[ai][ni][1] + bn),
                                  f2bf(acc[ai][ni][2] + bn), f2bf(acc[ai][ni][3] + bn));
        *reinterpret_cast<ushort4*>(
            &vtb[((size_t)(bb * NH + h) * HD + d) * SEQ + s0]) = pk;
      }
    }
  }
}

// ---------------------------------------------------------------------------
// Kernel 2: flash attention, Q == K (pre-scaled), FIXED-max base-2 softmax.
// XCD-affinity grid: all 32 q-blocks of a bh on one XCD (K/V L2-resident).
// Wave-private k-split (16 k-rows/wave) -> disjoint strips, NO barriers in
// main loop. K+V staged via global_load_lds, triple-buffered, counted
// vmcnt(8); register-level ds_read prefetch one tile ahead. PV pair-merged
// into K=32 MFMA. Cross-wave O-reduce once at epilogue.
// ---------------------------------------------------------------------------
__global__ __launch_bounds__(256) void attn_kernel(
    const unsigned short* __restrict__ qb, const unsigned short* __restrict__ vtb,
    unsigned short* __restrict__ ao) {
  __shared__ alignas(16) char pool[49152];   // 3 bufs x (4 waves x 4KB); epilogue reuses
  __shared__ alignas(16) float lsum[4][64];

  const int tid = threadIdx.x;
  const int lane = tid & 63, wid = tid >> 6;
  const int g = lane >> 4, c = lane & 15;

  // XCD-grouped decode: wg = xcd + 8*(qblk + 32*bh_local), bh = xcd*6+bh_local
  const int wg = blockIdx.x;
  const int xcd = wg & 7;
  const int idx = wg >> 3;                 // 0..191
  const int bh = xcd * 6 + (idx >> 5);
  const int qs0 = (idx & 31) * 64;
  const size_t base = (size_t)bh * SEQ * HD;

  // Q B-frags: lane (c,g) holds Q[qs0+jq*16+c][ks*32+g*8..+7]
  bf16x8 qf[4][2];
#pragma unroll
  for (int jq = 0; jq < 4; ++jq) {
    const unsigned short* qrow = &qb[base + (size_t)(qs0 + jq * 16 + c) * HD + g * 8];
    qf[jq][0] = *reinterpret_cast<const bf16x8*>(qrow);
    qf[jq][1] = *reinterpret_cast<const bf16x8*>(qrow + 32);
  }

  const char* qbB = (const char*)qb;
  const char* vtB = (const char*)vtb;
  auto bufp = [&](int b) -> char* { return pool + b * 16384 + wid * 4096; };
  // Stage tile kt's quarter for THIS wave into buffer buf (wave-private strip).
  auto stage = [&](int kt, int buf) {
    char* strip = bufp(buf);
    const size_t kQ = (base + (size_t)(kt * 64 + wid * 16) * HD) * 2;
#pragma unroll
    for (int i = 0; i < 2; ++i) {
      const int o = i * 1024 + lane * 16;
      const int swz = o ^ (((o >> 7) & 7) << 4);
      gload_lds16(qbB + kQ + swz, strip + o);
    }
#pragma unroll
    for (int i = 0; i < 2; ++i) {
      const int o = i * 1024 + lane * 16;
      const int row = o >> 5, half = (o >> 4) & 1;
      const int srcoff = (half ^ ((row >> 2) & 1)) << 4;
      gload_lds16(vtB + ((size_t)(bh * HD + row) * SEQ) * 2 + (size_t)kt * 128 + wid * 32 + srcoff,
                  strip + 2048 + o);
    }
  };

  const int cswz = (c & 7) << 4;
  const int vswz = (g * 8) ^ (((c >> 2) & 1) << 4);
  auto loadK = [&](const char* strip, bf16x8* kf) {
    kf[0] = *reinterpret_cast<const bf16x8*>(strip + c * 128 + ((g * 16) ^ cswz));
    kf[1] = *reinterpret_cast<const bf16x8*>(strip + c * 128 + ((64 + g * 16) ^ cswz));
  };
  auto loadV = [&](const char* strip, bf16x4* vf) {
#pragma unroll
    for (int dn = 0; dn < 4; ++dn)
      vf[dn] = *reinterpret_cast<const bf16x4*>(strip + 2048 + (dn * 16 + c) * 32 + vswz);
  };

  float l_p[4] = {};
  f32x4 o_acc[4][4] = {};  // [dn][jq]: O[d=dn*16+4g+r][q=jq*16+c], partial over wid's k

  auto qk = [&](const bf16x8* kf, f32x4* s) {
    __builtin_amdgcn_s_setprio(1);
#pragma unroll
    for (int jq = 0; jq < 4; ++jq)
      s[jq] = __builtin_amdgcn_mfma_f32_16x16x32_bf16(kf[0], qf[jq][0], s[jq], 0, 0, 0);
#pragma unroll
    for (int jq = 0; jq < 4; ++jq)
      s[jq] = __builtin_amdgcn_mfma_f32_16x16x32_bf16(kf[1], qf[jq][1], s[jq], 0, 0, 0);
    __builtin_amdgcn_s_setprio(0);
  };
  auto expcvt = [&](const f32x4* s, bf16x4* pb) {
#pragma unroll
    for (int jq = 0; jq < 4; ++jq) {
      float p0 = __builtin_amdgcn_exp2f(s[jq][0]);
      float p1 = __builtin_amdgcn_exp2f(s[jq][1]);
      float p2 = __builtin_amdgcn_exp2f(s[jq][2]);
      float p3 = __builtin_amdgcn_exp2f(s[jq][3]);
      l_p[jq] += (p0 + p1) + (p2 + p3);
      uint2 wv = make_uint2(cvt_pk_bf16(p0, p1), cvt_pk_bf16(p2, p3));
      pb[jq] = *reinterpret_cast<bf16x4*>(&wv);
    }
  };

  bf16x8 kf0[2], kf1[2], kfn[2];
  bf16x4 vf0[4], vf1[4], vfn[4];

  stage(0, 0); stage(1, 1); stage(2, 2);
  asm volatile("s_waitcnt vmcnt(8)" ::: "memory");   // tile 0 landed
  __builtin_amdgcn_sched_barrier(0);
  loadK(bufp(0), kf0); loadV(bufp(0), vf0);

  for (int kt = 0; kt < 32; kt += 2) {
    const char* sb1 = bufp((kt + 1) % 3);
    const char* sb2 = bufp((kt + 2) % 3);

    // ---- QK even tile (regs preloaded) ----
    f32x4 sa0[4] = {};
    qk(kf0, sa0);

    // stage kt+3 into buf kt%3 (kf0/vf0 reads retired via qk's lgkm wait)
    asm volatile("s_waitcnt lgkmcnt(0)" ::: "memory");
    __builtin_amdgcn_sched_barrier(0);
    stage((kt + 3) & 31, kt % 3);

    // wait tile kt+1 landed; prefetch its regs (overlaps exp2 below)
    asm volatile("s_waitcnt vmcnt(8)" ::: "memory");
    __builtin_amdgcn_sched_barrier(0);
    loadK(sb1, kf1); loadV(sb1, vf1);

    bf16x4 pb0[4];
    expcvt(sa0, pb0);

    // ---- QK odd tile ----
    f32x4 sa1[4] = {};
    qk(kf1, sa1);

    // stage kt+4 into buf (kt+1)%3
    asm volatile("s_waitcnt lgkmcnt(0)" ::: "memory");
    __builtin_amdgcn_sched_barrier(0);
    stage((kt + 4) & 31, (kt + 1) % 3);

    // wait tile kt+2 landed; prefetch next even tile's regs (overlaps exp2+PV)
    asm volatile("s_waitcnt vmcnt(8)" ::: "memory");
    __builtin_amdgcn_sched_barrier(0);
    if (kt < 30) { loadK(sb2, kfn); loadV(sb2, vfn); }

    bf16x4 pb1[4];
    expcvt(sa1, pb1);

    // ---- PV pair: K=32, slots [even k(4g..4g+3) | odd k(4g..4g+3)] ----
    bf16x8 pvv[4];
#pragma unroll
    for (int jq = 0; jq < 4; ++jq) pvv[jq] = cat4(pb0[jq], pb1[jq]);
    __builtin_amdgcn_s_setprio(1);
#pragma unroll
    for (int dn = 0; dn < 4; ++dn) {
      const bf16x8 av = cat4(vf0[dn], vf1[dn]);
#pragma unroll
      for (int jq = 0; jq < 4; ++jq)
        o_acc[dn][jq] = __builtin_amdgcn_mfma_f32_16x16x32_bf16(av, pvv[jq], o_acc[dn][jq], 0, 0, 0);
    }
    __builtin_amdgcn_s_setprio(0);

    // rotate prefetched regs
    kf0[0] = kfn[0]; kf0[1] = kfn[1];
#pragma unroll
    for (int dn = 0; dn < 4; ++dn) vf0[dn] = vfn[dn];
  }

  // drain wrapped prefetch stages before pool reuse (per-wave), then sync all
  asm volatile("s_waitcnt vmcnt(0)" ::: "memory");
  __builtin_amdgcn_sched_barrier(0);

  // ---- epilogue: l reduce; cross-wave O reduction via single sA buffer ----
#pragma unroll
  for (int jq = 0; jq < 4; ++jq) {
    float v = l_p[jq];
    v += __shfl_xor(v, 16);
    v += __shfl_xor(v, 32);
    if (g == 0) lsum[wid][jq * 16 + c] = v;
  }
  __syncthreads();

  float* sA = (float*)pool;  // [64][68] f32 = 17408 B
  auto writeO = [&]() {
#pragma unroll
    for (int dn = 0; dn < 4; ++dn)
#pragma unroll
      for (int jq = 0; jq < 4; ++jq)
        *reinterpret_cast<f32x4*>(&sA[(jq * 16 + c) * 68 + dn * 16 + 4 * g]) = o_acc[dn][jq];
  };
  auto addO = [&]() {
#pragma unroll
    for (int dn = 0; dn < 4; ++dn)
#pragma unroll
      for (int jq = 0; jq < 4; ++jq)
        o_acc[dn][jq] += *reinterpret_cast<const f32x4*>(&sA[(jq * 16 + c) * 68 + dn * 16 + 4 * g]);
  };

#pragma unroll
  for (int w = 1; w < 4; ++w) {
    if (wid == w) writeO();
    __syncthreads();
    if (wid == 0) addO();
    __syncthreads();
  }
  if (wid == 0) {
    const int b = bh / NH, h = bh % NH;
    float linv[4];
#pragma unroll
    for (int jq = 0; jq < 4; ++jq) {
      const int q = jq * 16 + c;
      const float l = (lsum[0][q] + lsum[1][q]) + (lsum[2][q] + lsum[3][q]);
      linv[jq] = __builtin_amdgcn_rcpf(l);
    }
#pragma unroll
    for (int dn = 0; dn < 4; ++dn)
#pragma unroll
      for (int jq = 0; jq < 4; ++jq) {
        uint2 wv = make_uint2(
            cvt_pk_bf16(o_acc[dn][jq][0] * linv[jq], o_acc[dn][jq][1] * linv[jq]),
            cvt_pk_bf16(o_acc[dn][jq][2] * linv[jq], o_acc[dn][jq][3] * linv[jq]));
        *reinterpret_cast<uint2*>(
            &ao[((size_t)b * SEQ + qs0 + jq * 16 + c) * DM + h * HD + dn * 16 + 4 * g]) = wv;
      }
  }
}

// ---------------------------------------------------------------------------
// Kernel 3: out = ao @ pwb^T + proj_b (bf16 in, f32 out). Same staging as qkv.
// ---------------------------------------------------------------------------
__global__ __launch_bounds__(256) void proj_kernel(
    const unsigned short* __restrict__ ao, const unsigned short* __restrict__ pwb,
    const float* __restrict__ bias, float* __restrict__ out) {
  __shared__ alignas(16) char As[2][8192];
  __shared__ alignas(16) char Bs[2][8192];
  const int tid = threadIdx.x;
  const int lane = tid & 63, wid = tid >> 6;
  const int wr = wid >> 1, wc = wid & 1;
  const int g = lane >> 4, c = lane & 15;
  const int m0 = blockIdx.x * 128, n0 = blockIdx.y * 128;
  const char* Ab = (const char*)ao;
  const char* Bb = (const char*)pwb;

  const int o0 = tid * 16, o1 = tid * 16 + 4096;
  const int r0 = o0 >> 6, r1 = o1 >> 6;
  const int sw0 = (o0 & 63) ^ (((r0 >> 1) & 3) << 4);
  const int sw1 = (o1 & 63) ^ (((r1 >> 1) & 3) << 4);

  auto stage = [&](int kt, int buf) {
    const int k0b = kt * 64;
    gload_lds16(Ab + (size_t)(m0 + r0) * 1536 + k0b + sw0, &As[buf][o0]);
    gload_lds16(Bb + (size_t)(n0 + r0) * 1536 + k0b + sw0, &Bs[buf][o0]);
    gload_lds16(Ab + (size_t)(m0 + r1) * 1536 + k0b + sw1, &As[buf][o1]);
    gload_lds16(Bb + (size_t)(n0 + r1) * 1536 + k0b + sw1, &Bs[buf][o1]);
  };

  f32x4 acc[4][4] = {};
  stage(0, 0);

  for (int kt = 0; kt < 24; ++kt) {
    __syncthreads();
    if (kt < 23) stage(kt + 1, (kt + 1) & 1);
    const char* Ap = As[kt & 1];
    const char* Bp = Bs[kt & 1];
    bf16x8 a_f[4], b_f[4];
#pragma unroll
    for (int i = 0; i < 4; ++i) {
      const int ra = wr * 64 + i * 16 + c;
      const int rb = wc * 64 + i * 16 + c;
      a_f[i] = *reinterpret_cast<const bf16x8*>(Ap + ra * 64 + ((g ^ ((ra >> 1) & 3)) << 4));
      b_f[i] = *reinterpret_cast<const bf16x8*>(Bp + rb * 64 + ((g ^ ((rb >> 1) & 3)) << 4));
    }
#pragma unroll
    for (int ai = 0; ai < 4; ++ai)
#pragma unroll
      for (int ni = 0; ni < 4; ++ni)
        acc[ai][ni] = __builtin_amdgcn_mfma_f32_16x16x32_bf16(a_f[ai], b_f[ni], acc[ai][ni], 0, 0, 0);
  }

#pragma unroll
  for (int ni = 0; ni < 4; ++ni) {
    const int n = n0 + wc * 64 + ni * 16 + c;
    const float bn = bias[n];
#pragma unroll
    for (int ai = 0; ai < 4; ++ai)
#pragma unroll
      for (int r = 0; r < 4; ++r) {
        const int m = m0 + wr * 64 + ai * 16 + g * 4 + r;
        out[(size_t)m * DM + n] = acc[ai][ni][r] + bn;
      }
  }
}

extern "C" void kernel_launch(void* const* d_in, const int* in_sizes, int n_in,
                              void* d_out, int out_size, void* d_ws, size_t ws_size,
                              hipStream_t stream) {
  const float* x = (const float*)d_in[0];
  const float* qkv_w = (const float*)d_in[1];
  const float* qkv_b = (const float*)d_in[2];
  const float* proj_w = (const float*)d_in[3];
  const float* proj_b = (const float*)d_in[4];
  float* out = (float*)d_out;

  const size_t elems = (size_t)4 * NH * SEQ * HD;  // 6291456 = B*S*DM
  unsigned short* qbuf = (unsigned short*)d_ws;
  unsigned short* vtbuf = qbuf + elems;
  unsigned short* xbf = vtbuf + elems;       // aliases aobuf (disjoint lifetimes)
  unsigned short* aobuf = xbf;
  unsigned short* wqkvbf = xbf + elems;      // 1179648
  unsigned short* wprojbf = wqkvbf + (size_t)2 * DM * DM;  // 589824

  cvt_kernel<<<dim3(1024), 256, 0, stream>>>(x, xbf, (int)(elems / 8));
  cvt_kernel<<<dim3(576), 256, 0, stream>>>(qkv_w, wqkvbf, 2 * DM * DM / 8);
  cvt_kernel<<<dim3(288), 256, 0, stream>>>(proj_w, wprojbf, DM * DM / 8);

  qkv_kernel<<<dim3(64, 12), 256, 0, stream>>>(xbf, wqkvbf, qkv_b, qbuf, vtbuf);
  attn_kernel<<<dim3(1536), 256, 0, stream>>>(qbuf, vtbuf, aobuf);
  proj_kernel<<<dim3(64, 6), 256, 0, stream>>>(aobuf, wprojbf, proj_b, out);
}

// Round 9
// 132.938 us; speedup vs baseline: 1.4097x; 1.2415x over previous
//
#include <hip/hip_runtime.h>
#include <hip/hip_bf16.h>

#define NH 12
#define HD 64
#define SEQ 2048
#define DM 768

typedef __attribute__((ext_vector_type(8))) short bf16x8;
typedef __attribute__((ext_vector_type(4))) short bf16x4;
typedef __attribute__((ext_vector_type(4))) float f32x4;

static __device__ __forceinline__ unsigned short f2bf(float f) {
  unsigned int u = __float_as_uint(f);
  u += 0x7fff + ((u >> 16) & 1);   // round-to-nearest-even
  return (unsigned short)(u >> 16);
}

static __device__ __forceinline__ unsigned cvt_pk_bf16(float lo, float hi) {
  unsigned r;
  asm("v_cvt_pk_bf16_f32 %0, %1, %2" : "=v"(r) : "v"(lo), "v"(hi));
  return r;
}

static __device__ __forceinline__ void gload_lds16(const void* g, void* l) {
  __builtin_amdgcn_global_load_lds(
      (const __attribute__((address_space(1))) void*)g,
      (__attribute__((address_space(3))) void*)l, 16, 0, 0);
}

// 16x16x16 bf16 MFMA (K=16): guarded builtin w/ asm fallback (verified in R4).
static __device__ __forceinline__ f32x4 mfma16(bf16x4 a, bf16x4 b, f32x4 c) {
#if __has_builtin(__builtin_amdgcn_mfma_f32_16x16x16bf16_1k)
  return __builtin_amdgcn_mfma_f32_16x16x16bf16_1k(a, b, c, 0, 0, 0);
#elif __has_builtin(__builtin_amdgcn_mfma_f32_16x16x16_bf16)
  return __builtin_amdgcn_mfma_f32_16x16x16_bf16(a, b, c, 0, 0, 0);
#else
  asm("v_mfma_f32_16x16x16_bf16 %0, %1, %2, %0" : "+v"(c) : "v"(a), "v"(b));
  return c;
#endif
}

// q-store scale: sqrt(log2(e))/8 — folds the 1/64 attention scale and the
// base-2 exp conversion into q at the QKV store.
#define QSCALE 0.15014030f

// ---------------------------------------------------------------------------
// Kernel 0: f32 -> bf16 bulk convert, 3 segments in one launch (x, w_qkv,
// w_proj), grid-stride over the virtual concatenation.
// ---------------------------------------------------------------------------
__global__ __launch_bounds__(256) void cvt3_kernel(
    const float* __restrict__ s0, unsigned short* __restrict__ d0, int n0,
    const float* __restrict__ s1, unsigned short* __restrict__ d1, int n1,
    const float* __restrict__ s2, unsigned short* __restrict__ d2, int n2) {
  int i = blockIdx.x * 256 + threadIdx.x;
  const int stride = gridDim.x * 256;
  const int ntot = n0 + n1 + n2;
  for (; i < ntot; i += stride) {
    const float* src;
    unsigned short* dst;
    int j = i;
    if (j < n0) { src = s0; dst = d0; }
    else if (j < n0 + n1) { j -= n0; src = s1; dst = d1; }
    else { j -= n0 + n1; src = s2; dst = d2; }
    const float4 a = reinterpret_cast<const float4*>(src)[j * 2];
    const float4 b = reinterpret_cast<const float4*>(src)[j * 2 + 1];
    ushort4 lo = make_ushort4(f2bf(a.x), f2bf(a.y), f2bf(a.z), f2bf(a.w));
    ushort4 hi = make_ushort4(f2bf(b.x), f2bf(b.y), f2bf(b.z), f2bf(b.w));
    reinterpret_cast<ushort4*>(dst)[j * 2] = lo;
    reinterpret_cast<ushort4*>(dst)[j * 2 + 1] = hi;
  }
}

// ---------------------------------------------------------------------------
// Kernel 1: qkv = xb @ wb^T + b (bf16 in). 128x128 tile, BK=32, dbuf LDS via
// global_load_lds (slot-swizzled source + read; 1 syncthreads per K-step).
// q stored (B,H,S,HD) bf16 pre-scaled by QSCALE; v stored (B,H,HD,S) bf16.
// ---------------------------------------------------------------------------
__global__ __launch_bounds__(256) void qkv_kernel(
    const unsigned short* __restrict__ xb, const unsigned short* __restrict__ wb,
    const float* __restrict__ bias,
    unsigned short* __restrict__ qb, unsigned short* __restrict__ vtb) {
  __shared__ alignas(16) char As[2][8192];   // [128 rows][64B], slot-swizzled
  __shared__ alignas(16) char Bs[2][8192];
  const int tid = threadIdx.x;
  const int lane = tid & 63, wid = tid >> 6;
  const int wr = wid >> 1, wc = wid & 1;
  const int g = lane >> 4, c = lane & 15;
  const int m0 = blockIdx.x * 128, n0 = blockIdx.y * 128;
  const char* Ab = (const char*)xb;
  const char* Bb = (const char*)wb;

  const int o0 = tid * 16, o1 = tid * 16 + 4096;
  const int r0 = o0 >> 6, r1 = o1 >> 6;
  const int sw0 = (o0 & 63) ^ (((r0 >> 1) & 3) << 4);
  const int sw1 = (o1 & 63) ^ (((r1 >> 1) & 3) << 4);

  auto stage = [&](int kt, int buf) {
    const int k0b = kt * 64;
    gload_lds16(Ab + (size_t)(m0 + r0) * 1536 + k0b + sw0, &As[buf][o0]);
    gload_lds16(Bb + (size_t)(n0 + r0) * 1536 + k0b + sw0, &Bs[buf][o0]);
    gload_lds16(Ab + (size_t)(m0 + r1) * 1536 + k0b + sw1, &As[buf][o1]);
    gload_lds16(Bb + (size_t)(n0 + r1) * 1536 + k0b + sw1, &Bs[buf][o1]);
  };

  f32x4 acc[4][4] = {};
  stage(0, 0);

  for (int kt = 0; kt < 24; ++kt) {
    __syncthreads();                       // drains vmcnt: stage(kt) landed
    if (kt < 23) stage(kt + 1, (kt + 1) & 1);
    const char* Ap = As[kt & 1];
    const char* Bp = Bs[kt & 1];
    bf16x8 a_f[4], b_f[4];
#pragma unroll
    for (int i = 0; i < 4; ++i) {
      const int ra = wr * 64 + i * 16 + c;
      const int rb = wc * 64 + i * 16 + c;
      a_f[i] = *reinterpret_cast<const bf16x8*>(Ap + ra * 64 + ((g ^ ((ra >> 1) & 3)) << 4));
      b_f[i] = *reinterpret_cast<const bf16x8*>(Bp + rb * 64 + ((g ^ ((rb >> 1) & 3)) << 4));
    }
#pragma unroll
    for (int ai = 0; ai < 4; ++ai)
#pragma unroll
      for (int ni = 0; ni < 4; ++ni)
        acc[ai][ni] = __builtin_amdgcn_mfma_f32_16x16x32_bf16(a_f[ai], b_f[ni], acc[ai][ni], 0, 0, 0);
  }

#pragma unroll
  for (int ni = 0; ni < 4; ++ni) {
    const int n = n0 + wc * 64 + ni * 16 + c;
    const float bn = bias[n];
    if (n < DM) {  // q path: (B,H,S,HD), pre-scaled
      const int h = n >> 6, d = n & 63;
#pragma unroll
      for (int ai = 0; ai < 4; ++ai)
#pragma unroll
        for (int r = 0; r < 4; ++r) {
          const int m = m0 + wr * 64 + ai * 16 + g * 4 + r;
          const int bb = m >> 11, s = m & 2047;
          qb[(((size_t)(bb * NH + h)) * SEQ + s) * HD + d] = f2bf((acc[ai][ni][r] + bn) * QSCALE);
        }
    } else {  // v path: transposed (B,H,HD,S)
      const int nn = n - DM;
      const int h = nn >> 6, d = nn & 63;
#pragma unroll
      for (int ai = 0; ai < 4; ++ai) {
        const int m_base = m0 + wr * 64 + ai * 16 + g * 4;
        const int bb = m_base >> 11, s0 = m_base & 2047;
        ushort4 pk = make_ushort4(f2bf(acc[ai][ni][0] + bn), f2bf(acc[ai][ni][1] + bn),
                                  f2bf(acc[ai][ni][2] + bn), f2bf(acc[ai][ni][3] + bn));
        *reinterpret_cast<ushort4*>(
            &vtb[((size_t)(bb * NH + h) * HD + d) * SEQ + s0]) = pk;
      }
    }
  }
}

// ---------------------------------------------------------------------------
// Kernel 2: flash attention, Q == K (pre-scaled), FIXED-max base-2 softmax.
// 2x2 wave split: wave (wq,wk) owns 32 q-rows x 32 k-rows of each 64-tile.
// Per-wave state fits 128 unified regs -> 4 waves/SIMD; LDS = 32768 exactly
// (2 shared 16KB bufs) -> 4+ blocks/CU. One barrier + vmcnt(0) per tile;
// prefetch window = full tile compute, data L2-resident (XCD-affinity grid).
// ---------------------------------------------------------------------------
__global__ __launch_bounds__(256, 4) void attn_kernel(
    const unsigned short* __restrict__ qb, const unsigned short* __restrict__ vtb,
    unsigned short* __restrict__ ao) {
  __shared__ alignas(16) char pool[2][16384];   // [buf][ K 8KB | V^T 8KB ]

  const int tid = threadIdx.x;
  const int lane = tid & 63, wid = tid >> 6;
  const int g = lane >> 4, c = lane & 15;
  const int wq = wid >> 1, wk = wid & 1;

  // XCD-grouped decode: all 32 q-blocks of a bh on one XCD
  const int wg = blockIdx.x;
  const int xcd = wg & 7;
  const int idx = wg >> 3;                 // 0..191
  const int bh = xcd * 6 + (idx >> 5);
  const int qs0 = (idx & 31) * 64;
  const size_t base = (size_t)bh * SEQ * HD;

  // Q B-frags: lane (c,g) holds Q[qs0+wq*32+jq*16+c][ks*32+g*8..+7]
  bf16x8 qf[2][2];
#pragma unroll
  for (int jq = 0; jq < 2; ++jq) {
    const unsigned short* qrow = &qb[base + (size_t)(qs0 + wq * 32 + jq * 16 + c) * HD + g * 8];
    qf[jq][0] = *reinterpret_cast<const bf16x8*>(qrow);
    qf[jq][1] = *reinterpret_cast<const bf16x8*>(qrow + 32);
  }

  // Shared staging: K tile (rows t*64..+64, swizzled cols) into [0,8192);
  // V^T tile (d rows 0..64, k-cols of tile t, swizzled) into [8192,16384).
  const char* qbB = (const char*)qb;
  const char* vtB = (const char*)vtb;
  const int oK0 = tid * 16, oK1 = tid * 16 + 4096;
  const int swK0 = oK0 ^ (((oK0 >> 7) & 7) << 4);
  const int swK1 = oK1 ^ (((oK1 >> 7) & 7) << 4);
  const int oV0 = tid * 16, oV1 = tid * 16 + 4096;   // within V region
  const int rV0 = oV0 >> 7, rV1 = oV1 >> 7;
  const int swV0 = (oV0 & 127) ^ (((rV0) & 7) << 4);
  const int swV1 = (oV1 & 127) ^ (((rV1) & 7) << 4);

  auto stage = [&](int t, int buf) {
    char* P = pool[buf];
    const size_t kQ = base * 2 + (size_t)t * 8192;   // K tile: contiguous 8KB
    gload_lds16(qbB + kQ + swK0, P + oK0);
    gload_lds16(qbB + kQ + swK1, P + oK1);
    gload_lds16(vtB + ((size_t)(bh * HD + rV0) * SEQ + t * 64) * 2 + swV0, P + 8192 + oV0);
    gload_lds16(vtB + ((size_t)(bh * HD + rV1) * SEQ + t * 64) * 2 + swV1, P + 8192 + oV1);
  };

  float l_p[2] = {0.f, 0.f};
  f32x4 o_acc[4][2] = {};  // [dn][jq]: O[d=dn*16+4g+r][q=qs0+wq*32+jq*16+c], partial wk

  const int cswz = (c & 7) << 4;

  stage(0, 0);
  asm volatile("s_waitcnt vmcnt(0)" ::: "memory");
  __builtin_amdgcn_sched_barrier(0);
  __builtin_amdgcn_s_barrier();

  for (int t = 0; t < 32; ++t) {
    const char* P = pool[t & 1];
    if (t < 31) stage(t + 1, (t + 1) & 1);

    // ---- S^T = K Q^T over this wave's 32 k-rows ----
    f32x4 sa[2][2] = {};
    __builtin_amdgcn_s_setprio(1);
#pragma unroll
    for (int jp = 0; jp < 2; ++jp) {
      const int krow = wk * 32 + jp * 16 + c;
      const bf16x8 kf0 = *reinterpret_cast<const bf16x8*>(P + krow * 128 + ((g * 16) ^ cswz));
      const bf16x8 kf1 = *reinterpret_cast<const bf16x8*>(P + krow * 128 + ((64 + g * 16) ^ cswz));
#pragma unroll
      for (int jq = 0; jq < 2; ++jq) {
        sa[jp][jq] = __builtin_amdgcn_mfma_f32_16x16x32_bf16(kf0, qf[jq][0], sa[jp][jq], 0, 0, 0);
        sa[jp][jq] = __builtin_amdgcn_mfma_f32_16x16x32_bf16(kf1, qf[jq][1], sa[jp][jq], 0, 0, 0);
      }
    }
    __builtin_amdgcn_s_setprio(0);

    // ---- fixed-max base-2 softmax: P = 2^s (in-register) ----
    bf16x4 pb[2][2];
#pragma unroll
    for (int jp = 0; jp < 2; ++jp)
#pragma unroll
      for (int jq = 0; jq < 2; ++jq) {
        float p0 = __builtin_amdgcn_exp2f(sa[jp][jq][0]);
        float p1 = __builtin_amdgcn_exp2f(sa[jp][jq][1]);
        float p2 = __builtin_amdgcn_exp2f(sa[jp][jq][2]);
        float p3 = __builtin_amdgcn_exp2f(sa[jp][jq][3]);
        l_p[jq] += (p0 + p1) + (p2 + p3);
        uint2 wv = make_uint2(cvt_pk_bf16(p0, p1), cvt_pk_bf16(p2, p3));
        pb[jp][jq] = *reinterpret_cast<bf16x4*>(&wv);
      }

    // ---- O^T += V^T P : per-tile K=16 MFMA, A-frags from shared V ----
    __builtin_amdgcn_s_setprio(1);
#pragma unroll
    for (int dn = 0; dn < 4; ++dn) {
      const int vrow = dn * 16 + c;
      const bf16x4 vf0 = *reinterpret_cast<const bf16x4*>(
          P + 8192 + vrow * 128 + ((wk * 64 + 8 * g) ^ cswz));
      const bf16x4 vf1 = *reinterpret_cast<const bf16x4*>(
          P + 8192 + vrow * 128 + ((wk * 64 + 32 + 8 * g) ^ cswz));
#pragma unroll
      for (int jq = 0; jq < 2; ++jq) {
        o_acc[dn][jq] = mfma16(vf0, pb[0][jq], o_acc[dn][jq]);
        o_acc[dn][jq] = mfma16(vf1, pb[1][jq], o_acc[dn][jq]);
      }
    }
    __builtin_amdgcn_s_setprio(0);

    // tile t+1 landed; all waves done reading buf[t&1]
    asm volatile("s_waitcnt vmcnt(0)" ::: "memory");
    __builtin_amdgcn_sched_barrier(0);
    __builtin_amdgcn_s_barrier();
  }

  // ---- epilogue: reduce l over g; O + l over the wk pair via LDS ----
#pragma unroll
  for (int jq = 0; jq < 2; ++jq) {
    float v = l_p[jq];
    v += __shfl_xor(v, 16);
    v += __shfl_xor(v, 32);
    l_p[jq] = v;
  }

  float* ex = (float*)(pool[0] + wq * 16384);  // [32 q][68] f32 + l[32]
  float* exl = ex + 32 * 68;
  if (wk == 1) {
#pragma unroll
    for (int dn = 0; dn < 4; ++dn)
#pragma unroll
      for (int jq = 0; jq < 2; ++jq)
        *reinterpret_cast<f32x4*>(&ex[(jq * 16 + c) * 68 + dn * 16 + 4 * g]) = o_acc[dn][jq];
    if (g == 0) {
      exl[c] = l_p[0];
      exl[16 + c] = l_p[1];
    }
  }
  __syncthreads();
  if (wk == 0) {
    const int b = bh / NH, h = bh % NH;
    float linv[2];
#pragma unroll
    for (int jq = 0; jq < 2; ++jq)
      linv[jq] = __builtin_amdgcn_rcpf(l_p[jq] + exl[jq * 16 + c]);
#pragma unroll
    for (int dn = 0; dn < 4; ++dn)
#pragma unroll
      for (int jq = 0; jq < 2; ++jq) {
        f32x4 o = o_acc[dn][jq];
        o += *reinterpret_cast<const f32x4*>(&ex[(jq * 16 + c) * 68 + dn * 16 + 4 * g]);
        uint2 wv = make_uint2(cvt_pk_bf16(o[0] * linv[jq], o[1] * linv[jq]),
                              cvt_pk_bf16(o[2] * linv[jq], o[3] * linv[jq]));
        *reinterpret_cast<uint2*>(
            &ao[((size_t)b * SEQ + qs0 + wq * 32 + jq * 16 + c) * DM + h * HD + dn * 16 + 4 * g]) = wv;
      }
  }
}

// ---------------------------------------------------------------------------
// Kernel 3: out = ao @ pwb^T + proj_b (bf16 in, f32 out). Same staging as qkv.
// ---------------------------------------------------------------------------
__global__ __launch_bounds__(256) void proj_kernel(
    const unsigned short* __restrict__ ao, const unsigned short* __restrict__ pwb,
    const float* __restrict__ bias, float* __restrict__ out) {
  __shared__ alignas(16) char As[2][8192];
  __shared__ alignas(16) char Bs[2][8192];
  const int tid = threadIdx.x;
  const int lane = tid & 63, wid = tid >> 6;
  const int wr = wid >> 1, wc = wid & 1;
  const int g = lane >> 4, c = lane & 15;
  const int m0 = blockIdx.x * 128, n0 = blockIdx.y * 128;
  const char* Ab = (const char*)ao;
  const char* Bb = (const char*)pwb;

  const int o0 = tid * 16, o1 = tid * 16 + 4096;
  const int r0 = o0 >> 6, r1 = o1 >> 6;
  const int sw0 = (o0 & 63) ^ (((r0 >> 1) & 3) << 4);
  const int sw1 = (o1 & 63) ^ (((r1 >> 1) & 3) << 4);

  auto stage = [&](int kt, int buf) {
    const int k0b = kt * 64;
    gload_lds16(Ab + (size_t)(m0 + r0) * 1536 + k0b + sw0, &As[buf][o0]);
    gload_lds16(Bb + (size_t)(n0 + r0) * 1536 + k0b + sw0, &Bs[buf][o0]);
    gload_lds16(Ab + (size_t)(m0 + r1) * 1536 + k0b + sw1, &As[buf][o1]);
    gload_lds16(Bb + (size_t)(n0 + r1) * 1536 + k0b + sw1, &Bs[buf][o1]);
  };

  f32x4 acc[4][4] = {};
  stage(0, 0);

  for (int kt = 0; kt < 24; ++kt) {
    __syncthreads();
    if (kt < 23) stage(kt + 1, (kt + 1) & 1);
    const char* Ap = As[kt & 1];
    const char* Bp = Bs[kt & 1];
    bf16x8 a_f[4], b_f[4];
#pragma unroll
    for (int i = 0; i < 4; ++i) {
      const int ra = wr * 64 + i * 16 + c;
      const int rb = wc * 64 + i * 16 + c;
      a_f[i] = *reinterpret_cast<const bf16x8*>(Ap + ra * 64 + ((g ^ ((ra >> 1) & 3)) << 4));
      b_f[i] = *reinterpret_cast<const bf16x8*>(Bp + rb * 64 + ((g ^ ((rb >> 1) & 3)) << 4));
    }
#pragma unroll
    for (int ai = 0; ai < 4; ++ai)
#pragma unroll
      for (int ni = 0; ni < 4; ++ni)
        acc[ai][ni] = __builtin_amdgcn_mfma_f32_16x16x32_bf16(a_f[ai], b_f[ni], acc[ai][ni], 0, 0, 0);
  }

#pragma unroll
  for (int ni = 0; ni < 4; ++ni) {
    const int n = n0 + wc * 64 + ni * 16 + c;
    const float bn = bias[n];
#pragma unroll
    for (int ai = 0; ai < 4; ++ai)
#pragma unroll
      for (int r = 0; r < 4; ++r) {
        const int m = m0 + wr * 64 + ai * 16 + g * 4 + r;
        out[(size_t)m * DM + n] = acc[ai][ni][r] + bn;
      }
  }
}

extern "C" void kernel_launch(void* const* d_in, const int* in_sizes, int n_in,
                              void* d_out, int out_size, void* d_ws, size_t ws_size,
                              hipStream_t stream) {
  const float* x = (const float*)d_in[0];
  const float* qkv_w = (const float*)d_in[1];
  const float* qkv_b = (const float*)d_in[2];
  const float* proj_w = (const float*)d_in[3];
  const float* proj_b = (const float*)d_in[4];
  float* out = (float*)d_out;

  const size_t elems = (size_t)4 * NH * SEQ * HD;  // 6291456 = B*S*DM
  unsigned short* qbuf = (unsigned short*)d_ws;
  unsigned short* vtbuf = qbuf + elems;
  unsigned short* xbf = vtbuf + elems;       // aliases aobuf (disjoint lifetimes)
  unsigned short* aobuf = xbf;
  unsigned short* wqkvbf = xbf + elems;      // 1179648
  unsigned short* wprojbf = wqkvbf + (size_t)2 * DM * DM;  // 589824

  cvt3_kernel<<<dim3(2048), 256, 0, stream>>>(
      x, xbf, (int)(elems / 8),
      qkv_w, wqkvbf, 2 * DM * DM / 8,
      proj_w, wprojbf, DM * DM / 8);

  qkv_kernel<<<dim3(64, 12), 256, 0, stream>>>(xbf, wqkvbf, qkv_b, qbuf, vtbuf);
  attn_kernel<<<dim3(1536), 256, 0, stream>>>(qbuf, vtbuf, aobuf);
  proj_kernel<<<dim3(64, 6), 256, 0, stream>>>(aobuf, wprojbf, proj_b, out);
}